// Round 4
// baseline (428.471 us; speedup 1.0000x reference)
//
#include <hip/hip_runtime.h>

// ---------------------------------------------------------------------------
// XposMultiheadAttention (B=8, T=S=1024, E=1024, H=16, D=64) — bf16 MFMA r4
//  * qkv projections: ONE launch (grid 512x3), A staged fp32->bf16 in-kernel
//    (reg-stage + swizzled ds_write), W via global_load_lds. Epilogue fuses
//    bias / 0.125 / xPos rotation; out (B,H,T,D) bf16.
//  * flash attn: defer-max (THR=8) + lane-local l partials (no per-tile
//    cross-lane shuffles in the common path).
//  * ws = 72.5 MB (limit learned in r2/r3: between 101.2 and 104.5 MB).
// ---------------------------------------------------------------------------

#define BSZ  8
#define SEQ  1024
#define EMB  1024
#define NH   16
#define HD   64
#define HALF 32
#define BH   (BSZ*NH)
#define MROWS (BSZ*SEQ)

typedef __attribute__((ext_vector_type(4))) float f32x4;
typedef __attribute__((ext_vector_type(8))) short bf16x8;
typedef __attribute__((ext_vector_type(8))) unsigned short u16x8;

__device__ __forceinline__ ushort f2bf(float f) {
    union { float f; unsigned u; } v; v.f = f;
    return (ushort)((v.u + 0x7FFFu + ((v.u >> 16) & 1u)) >> 16);
}

// async global->LDS, 16B per lane; lds ptr must be the wave-uniform base.
__device__ __forceinline__ void async16(void* lds, const void* g) {
    __builtin_amdgcn_global_load_lds(
        (const __attribute__((address_space(1))) unsigned int*)g,
        (__attribute__((address_space(3))) unsigned int*)lds, 16, 0, 0);
}

// ---------------------------------------------------------------------------
// 4 weight casts in one launch (grid y = 0..3).
// ---------------------------------------------------------------------------
__global__ __launch_bounds__(256)
void castw_kernel(const float* __restrict__ w0, const float* __restrict__ w1,
                  const float* __restrict__ w2, const float* __restrict__ w3,
                  ushort* __restrict__ d0, ushort* __restrict__ d1,
                  ushort* __restrict__ d2, ushort* __restrict__ d3, int n4) {
    int i = blockIdx.x * 256 + threadIdx.x;
    if (i >= n4) return;
    const float* s = blockIdx.y == 0 ? w0 : blockIdx.y == 1 ? w1
                   : blockIdx.y == 2 ? w2 : w3;
    ushort* d = blockIdx.y == 0 ? d0 : blockIdx.y == 1 ? d1
              : blockIdx.y == 2 ? d2 : d3;
    float4 v = reinterpret_cast<const float4*>(s)[i];
    ushort4 o;
    o.x = f2bf(v.x); o.y = f2bf(v.y); o.z = f2bf(v.z); o.w = f2bf(v.w);
    reinterpret_cast<ushort4*>(d)[i] = o;
}

// ---------------------------------------------------------------------------
// xPos tables: [0]=sin*scale (q), [1]=cos*scale (q), [2]=sin/scale (k),
// [3]=cos/scale (k); each SEQ*HALF floats.
// ---------------------------------------------------------------------------
__global__ __launch_bounds__(256)
void xpos_tables_kernel(float* __restrict__ tab) {
    int idx = blockIdx.x * 256 + threadIdx.x;
    if (idx >= SEQ * HALF) return;
    int t = idx >> 5;
    int j = idx & 31;
    float s        = (2.0f * (float)j + 0.4f * (float)HD) / (1.4f * (float)HD);
    float pos      = (float)(t - SEQ / 2);
    float scale    = powf(s, pos * (1.0f / 1024.0f));
    float inv_freq = powf(10000.0f, -(float)j / (float)HALF);
    float ang      = (float)t * inv_freq;
    float sn = sinf(ang), cs = cosf(ang);
    float inv_scale = 1.0f / scale;
    tab[0 * SEQ * HALF + idx] = sn * scale;
    tab[1 * SEQ * HALF + idx] = cs * scale;
    tab[2 * SEQ * HALF + idx] = sn * inv_scale;
    tab[3 * SEQ * HALF + idx] = cs * inv_scale;
}

// ---------------------------------------------------------------------------
// Fused q/k/v projection: Y[m,n] = sum_k A[m,k]*W[n,k] + bias (+scale,+xpos).
// blockIdx.y: 0=q (0.125, xpos up), 1=k (xpos down), 2=v (bias only).
// 128x128 tile, BK=64, 4 waves (2x2, each 64x64 = 4x4 frags of 16x16x32).
// A: fp32 global -> regs -> bf16 -> swizzled ds_write_b128 (fused cast).
// W: bf16 global via global_load_lds, pre-swizzled source (rule 21).
// LDS element at byte (r*128+cb) holds global col ((cb ^ ((r&7)<<4))/2).
// ---------------------------------------------------------------------------
__global__ __launch_bounds__(256)
void qkv_gemm_kernel(const float* __restrict__ Aq, const float* __restrict__ Ak,
                     const float* __restrict__ Av,
                     const ushort* __restrict__ Wq, const ushort* __restrict__ Wk,
                     const ushort* __restrict__ Wv,
                     const float* __restrict__ bq, const float* __restrict__ bk,
                     const float* __restrict__ bv,
                     const float* __restrict__ tab,
                     ushort* __restrict__ oq, ushort* __restrict__ ok,
                     ushort* __restrict__ ov) {
    __shared__ ushort As[128 * 64];
    __shared__ ushort Bs[128 * 64];
    const int ymode = blockIdx.y;                 // 0=q,1=k,2=v
    const float*  A    = ymode == 0 ? Aq : ymode == 1 ? Ak : Av;
    const ushort* W    = ymode == 0 ? Wq : ymode == 1 ? Wk : Wv;
    const float*  bias = ymode == 0 ? bq : ymode == 1 ? bk : bv;
    ushort*       outp = ymode == 0 ? oq : ymode == 1 ? ok : ov;

    const int tid  = threadIdx.x;
    const int lane = tid & 63;
    const int w    = tid >> 6;
    const int g    = lane >> 4;
    const int c    = lane & 15;
    const int wr   = w >> 1, wc = w & 1;

    // XCD-contiguous remap (512 x-blocks, 8 XCDs).
    int lid = blockIdx.x;
    int wg  = (lid & 7) * 64 + (lid >> 3);
    const int row0 = (wg >> 3) * 128;
    const int col0 = (wg & 7) * 128;

    f32x4 acc[4][4] = {};

    // A staging ids: thread -> row ar (0..127), col-half ach (0 or 32).
    const int ar  = tid >> 1;
    const int ach = (tid & 1) * 32;
    const int asw = (ar & 7) << 4;

    // B staging: pre-swizzled global source for linear global_load_lds dest.
    int srow[4], scol[4];
    #pragma unroll
    for (int i = 0; i < 4; ++i) {
        int f = i * 4096 + tid * 16;
        int r = f >> 7, cb = f & 127;
        srow[i] = r;
        scol[i] = (cb ^ ((r & 7) << 4)) >> 1;
    }

    for (int k0 = 0; k0 < EMB; k0 += 64) {
        // --- A: load 8x float4 fp32, convert, 4x swizzled ds_write_b128 ---
        const float4* asrc = reinterpret_cast<const float4*>(
            &A[(size_t)(row0 + ar) * EMB + k0 + ach]);
        float4 av[8];
        #pragma unroll
        for (int i = 0; i < 8; ++i) av[i] = asrc[i];
        #pragma unroll
        for (int a = 0; a < 4; ++a) {
            u16x8 u;
            const float* pf = reinterpret_cast<const float*>(&av[2 * a]);
            #pragma unroll
            for (int e = 0; e < 8; ++e) u[e] = f2bf(pf[e]);
            int byt = ar * 128 + ((2 * (ach + 8 * a)) ^ asw);
            *reinterpret_cast<u16x8*>(reinterpret_cast<char*>(As) + byt) = u;
        }
        // --- B: async global->LDS ---
        #pragma unroll
        for (int i = 0; i < 4; ++i)
            async16(&Bs[i * 2048 + w * 512],
                    &W[(size_t)(col0 + srow[i]) * EMB + k0 + scol[i]]);
        __syncthreads();   // drains lgkm (A writes) + vmcnt (B async)

        #pragma unroll
        for (int ks = 0; ks < 2; ++ks) {
            bf16x8 af[4], bfr[4];
            #pragma unroll
            for (int mi = 0; mi < 4; ++mi) {
                int r = wr * 64 + mi * 16 + c;
                int byt = r * 128 + ((ks * 64 + g * 16) ^ ((r & 7) << 4));
                af[mi] = *reinterpret_cast<const bf16x8*>(
                    reinterpret_cast<const char*>(As) + byt);
            }
            #pragma unroll
            for (int ni = 0; ni < 4; ++ni) {
                int r = wc * 64 + ni * 16 + c;
                int byt = r * 128 + ((ks * 64 + g * 16) ^ ((r & 7) << 4));
                bfr[ni] = *reinterpret_cast<const bf16x8*>(
                    reinterpret_cast<const char*>(Bs) + byt);
            }
            #pragma unroll
            for (int mi = 0; mi < 4; ++mi)
                #pragma unroll
                for (int ni = 0; ni < 4; ++ni)
                    acc[mi][ni] = __builtin_amdgcn_mfma_f32_16x16x32_bf16(
                        af[mi], bfr[ni], acc[mi][ni], 0, 0, 0);
        }
        __syncthreads();
    }

    // Epilogue. C map (m89): col n = col0+wc*64+ni*16+c, row m = ...+g*4+r.
    #pragma unroll
    for (int ni = 0; ni < 4; ++ni) {
        int n = col0 + wc * 64 + ni * 16 + c;
        float bn = bias[n];
        #pragma unroll
        for (int mi = 0; mi < 4; ++mi) {
            #pragma unroll
            for (int r = 0; r < 4; ++r) {
                int m = row0 + wr * 64 + mi * 16 + g * 4 + r;
                float val = acc[mi][ni][r] + bn;
                if (ymode == 0) val *= 0.125f;         // HEAD_DIM^-0.5
                if (ymode != 2) {                      // xPos rotation
                    int t = m & (SEQ - 1);
                    int d = n & 63;
                    const int base = (ymode == 0 ? 0 : 2) * SEQ * HALF + t * HALF;
                    float sn = tab[base + (d >> 1)];
                    float cs = tab[base + SEQ * HALF + (d >> 1)];
                    float other = __shfl_xor(val, 1);  // partner col d^1
                    val = val * cs + ((d & 1) ? other * sn : -other * sn);
                }
                int b = m >> 10, t = m & 1023;
                int h = n >> 6,  d = n & 63;
                outp[(((size_t)b * NH + h) * SEQ + t) * HD + d] = f2bf(val);
            }
        }
    }
}

// ---------------------------------------------------------------------------
// V transpose: (B,H,T,D) bf16 -> (B,H,D,T) bf16, 64x64 tiles.
// ---------------------------------------------------------------------------
__global__ __launch_bounds__(256)
void vtrans_kernel(const ushort* __restrict__ v, ushort* __restrict__ vt) {
    __shared__ ushort T[64][72];
    const int tid = threadIdx.x;
    const int bh  = blockIdx.y;
    const int t0  = blockIdx.x * 64;
    const ushort* vb = &v[((size_t)bh * SEQ + t0) * HD];
    #pragma unroll
    for (int p = 0; p < 2; ++p) {
        int chunk = p * 256 + tid;
        int tl = chunk >> 3;
        int d8 = (chunk & 7) * 8;
        ushort tmp[8];
        *reinterpret_cast<uint4*>(tmp) =
            *reinterpret_cast<const uint4*>(&vb[tl * HD + d8]);
        #pragma unroll
        for (int j = 0; j < 8; ++j) T[d8 + j][tl] = tmp[j];
    }
    __syncthreads();
    ushort* ob = &vt[(size_t)bh * HD * SEQ + t0];
    #pragma unroll
    for (int p = 0; p < 2; ++p) {
        int chunk = p * 256 + tid;
        int dl = chunk >> 3;
        int t8 = (chunk & 7) * 8;
        *reinterpret_cast<uint4*>(&ob[(size_t)dl * SEQ + t8]) =
            *reinterpret_cast<const uint4*>(&T[dl][t8]);
    }
}

// ---------------------------------------------------------------------------
// Flash attention, bf16 MFMA, defer-max online softmax.
// Block = 64 q-rows of one (b,h); 4 waves x 16 q-rows. Q in regs; K and V^T
// 64x64 tiles double-buffered in swizzled LDS. Common path: NO cross-lane
// ops, no rescale (m frozen unless local max exceeds m+8; P bounded by e^8).
// l kept as lane-local partials, reduced once at the end.
// ---------------------------------------------------------------------------
__global__ __launch_bounds__(256)
void attn_kernel(const ushort* __restrict__ qg, const ushort* __restrict__ kg,
                 const ushort* __restrict__ vtg, ushort* __restrict__ og) {
    __shared__ ushort Ks[2 * 4096];
    __shared__ ushort Vs[2 * 4096];
    __shared__ ushort Ps[4096];
    const int tid  = threadIdx.x;
    const int lane = tid & 63;
    const int w    = tid >> 6;
    const int g    = lane >> 4;
    const int c    = lane & 15;

    int lid = blockIdx.x;                     // 2048 blocks
    int wg  = (lid & 7) * 256 + (lid >> 3);   // XCD-contiguous, bh-major
    const int bh = wg >> 4;
    const int q0 = (wg & 15) * 64;

    const ushort* qrow = &qg[((size_t)bh * SEQ + q0 + w * 16 + c) * HD];
    bf16x8 qf[2];
    qf[0] = *reinterpret_cast<const bf16x8*>(qrow + g * 8);
    qf[1] = *reinterpret_cast<const bf16x8*>(qrow + 32 + g * 8);

    float m_run[4], l_part[4];
    f32x4 oacc[4] = {};
    #pragma unroll
    for (int r = 0; r < 4; ++r) { m_run[r] = -1e30f; l_part[r] = 0.f; }

    int srow[2], scol[2];
    #pragma unroll
    for (int i = 0; i < 2; ++i) {
        int f = i * 4096 + tid * 16;
        int r = f >> 7, cb = f & 127;
        srow[i] = r; scol[i] = (cb ^ ((r & 7) << 4)) >> 1;
    }

    const ushort* kb  = &kg[(size_t)bh * SEQ * HD];
    const ushort* vtb = &vtg[(size_t)bh * HD * SEQ];

    auto stage = [&](int buf, int kt) {
        #pragma unroll
        for (int i = 0; i < 2; ++i) {
            async16(&Ks[buf * 4096 + i * 2048 + w * 512],
                    &kb[(size_t)(kt + srow[i]) * HD + scol[i]]);
            async16(&Vs[buf * 4096 + i * 2048 + w * 512],
                    &vtb[(size_t)srow[i] * SEQ + kt + scol[i]]);
        }
    };

    stage(0, 0);
    __syncthreads();

    char* pbase = reinterpret_cast<char*>(Ps) + w * 2048;

    for (int kt = 0; kt < SEQ; kt += 64) {
        const int cur = (kt >> 6) & 1;
        if (kt + 64 < SEQ) stage(cur ^ 1, kt + 64);  // prefetch overlaps compute

        const char* kbase = reinterpret_cast<const char*>(Ks) + cur * 8192;
        const char* vbase = reinterpret_cast<const char*>(Vs) + cur * 8192;

        // Scores: S[q=g*4+r][key=j*16+c]
        f32x4 s[4];
        #pragma unroll
        for (int j = 0; j < 4; ++j) {
            int key = j * 16 + c;
            int sw  = (key & 7) << 4;
            f32x4 a = {};
            #pragma unroll
            for (int ks = 0; ks < 2; ++ks) {
                bf16x8 kf = *reinterpret_cast<const bf16x8*>(
                    kbase + key * 128 + ((ks * 64 + g * 16) ^ sw));
                a = __builtin_amdgcn_mfma_f32_16x16x32_bf16(qf[ks], kf, a, 0, 0, 0);
            }
            s[j] = a;
        }

        // Defer-max: rescale only when some lane's local max exceeds m+8.
        float pmax[4];
        #pragma unroll
        for (int r = 0; r < 4; ++r)
            pmax[r] = fmaxf(fmaxf(s[0][r], s[1][r]), fmaxf(s[2][r], s[3][r]));
        int need = (pmax[0] > m_run[0] + 8.f) || (pmax[1] > m_run[1] + 8.f) ||
                   (pmax[2] > m_run[2] + 8.f) || (pmax[3] > m_run[3] + 8.f);
        if (__any(need)) {                    // wave-uniform branch (rare)
            #pragma unroll
            for (int r = 0; r < 4; ++r) {
                float mx = pmax[r];
                mx = fmaxf(mx, __shfl_xor(mx, 1));
                mx = fmaxf(mx, __shfl_xor(mx, 2));
                mx = fmaxf(mx, __shfl_xor(mx, 4));
                mx = fmaxf(mx, __shfl_xor(mx, 8));
                float mn = fmaxf(m_run[r], mx);
                float alpha = __expf(m_run[r] - mn);
                l_part[r] *= alpha;
                #pragma unroll
                for (int dblk = 0; dblk < 4; ++dblk) oacc[dblk][r] *= alpha;
                m_run[r] = mn;
            }
        }

        // P = exp(S - m), lane-local l partials, stage P (bf16, swizzled).
        #pragma unroll
        for (int r = 0; r < 4; ++r) {
            int q  = g * 4 + r;
            int sw = (q & 7) << 4;
            #pragma unroll
            for (int j = 0; j < 4; ++j) {
                float p = __expf(s[j][r] - m_run[r]);
                l_part[r] += p;
                int byt = q * 128 + (((j * 16 + c) * 2) ^ sw);
                *reinterpret_cast<ushort*>(pbase + byt) = f2bf(p);
            }
        }

        // PV: O[q][d] += P[q][key] * V^T[d][key]
        #pragma unroll
        for (int ks = 0; ks < 2; ++ks) {
            bf16x8 pf = *reinterpret_cast<const bf16x8*>(
                pbase + c * 128 + ((ks * 64 + g * 16) ^ ((c & 7) << 4)));
            #pragma unroll
            for (int dblk = 0; dblk < 4; ++dblk) {
                int d = dblk * 16 + c;
                bf16x8 vf = *reinterpret_cast<const bf16x8*>(
                    vbase + d * 128 + ((ks * 64 + g * 16) ^ ((d & 7) << 4)));
                oacc[dblk] = __builtin_amdgcn_mfma_f32_16x16x32_bf16(
                    pf, vf, oacc[dblk], 0, 0, 0);
            }
        }
        __syncthreads();   // drains prefetch vmcnt; all waves done with buf[cur]
    }

    // Epilogue: reduce l across the 16-lane row group, normalize, write bf16.
    #pragma unroll
    for (int r = 0; r < 4; ++r) {
        float rs = l_part[r];
        rs += __shfl_xor(rs, 1);
        rs += __shfl_xor(rs, 2);
        rs += __shfl_xor(rs, 4);
        rs += __shfl_xor(rs, 8);
        float inv = 1.f / rs;
        int q = q0 + w * 16 + g * 4 + r;
        #pragma unroll
        for (int dblk = 0; dblk < 4; ++dblk)
            og[((size_t)bh * SEQ + q) * HD + dblk * 16 + c] =
                f2bf(oacc[dblk][r] * inv);
    }
}

// ---------------------------------------------------------------------------
// Output projection: out[m,n] = sum_k AO[m,k]*Wo[n,k] + bo, fp32 (B,T,E).
// A gathered from (B,H,T,D) bf16 (BK=64 == one head, rows contiguous).
// ---------------------------------------------------------------------------
__global__ __launch_bounds__(256)
void outproj_kernel(const ushort* __restrict__ A, const ushort* __restrict__ W,
                    const float* __restrict__ bias, float* __restrict__ out) {
    __shared__ ushort As[128 * 64];
    __shared__ ushort Bs[128 * 64];
    const int tid  = threadIdx.x;
    const int lane = tid & 63;
    const int w    = tid >> 6;
    const int g    = lane >> 4;
    const int c    = lane & 15;
    const int wr   = w >> 1, wc = w & 1;

    int lid = blockIdx.x;
    int wg  = (lid & 7) * 64 + (lid >> 3);
    const int row0 = (wg >> 3) * 128;
    const int col0 = (wg & 7) * 128;

    f32x4 acc[4][4] = {};

    int srow[4], scol[4];
    #pragma unroll
    for (int i = 0; i < 4; ++i) {
        int f = i * 4096 + tid * 16;
        int r = f >> 7, cb = f & 127;
        srow[i] = r;
        scol[i] = (cb ^ ((r & 7) << 4)) >> 1;
    }

    for (int k0 = 0; k0 < EMB; k0 += 64) {
        int h = k0 >> 6;
        #pragma unroll
        for (int i = 0; i < 4; ++i)
            async16(&As[i * 2048 + w * 512],
                    &A[(((size_t)(row0 >> 10) * NH + h) * SEQ +
                        (row0 & 1023) + srow[i]) * HD + scol[i]]);
        #pragma unroll
        for (int i = 0; i < 4; ++i)
            async16(&Bs[i * 2048 + w * 512],
                    &W[(size_t)(col0 + srow[i]) * EMB + k0 + scol[i]]);
        __syncthreads();

        #pragma unroll
        for (int ks = 0; ks < 2; ++ks) {
            bf16x8 af[4], bfr[4];
            #pragma unroll
            for (int mi = 0; mi < 4; ++mi) {
                int r = wr * 64 + mi * 16 + c;
                int byt = r * 128 + ((ks * 64 + g * 16) ^ ((r & 7) << 4));
                af[mi] = *reinterpret_cast<const bf16x8*>(
                    reinterpret_cast<const char*>(As) + byt);
            }
            #pragma unroll
            for (int ni = 0; ni < 4; ++ni) {
                int r = wc * 64 + ni * 16 + c;
                int byt = r * 128 + ((ks * 64 + g * 16) ^ ((r & 7) << 4));
                bfr[ni] = *reinterpret_cast<const bf16x8*>(
                    reinterpret_cast<const char*>(Bs) + byt);
            }
            #pragma unroll
            for (int mi = 0; mi < 4; ++mi)
                #pragma unroll
                for (int ni = 0; ni < 4; ++ni)
                    acc[mi][ni] = __builtin_amdgcn_mfma_f32_16x16x32_bf16(
                        af[mi], bfr[ni], acc[mi][ni], 0, 0, 0);
        }
        __syncthreads();
    }

    #pragma unroll
    for (int ni = 0; ni < 4; ++ni) {
        int n = col0 + wc * 64 + ni * 16 + c;
        float bn = bias[n];
        #pragma unroll
        for (int mi = 0; mi < 4; ++mi) {
            #pragma unroll
            for (int r = 0; r < 4; ++r) {
                int m = row0 + wr * 64 + mi * 16 + g * 4 + r;
                out[(size_t)m * EMB + n] = acc[mi][ni][r] + bn;
            }
        }
    }
}

// ---------------------------------------------------------------------------
// Launch. ws (ushort units), 72.5 MB:
//   qb[NX] kb[NX] vb[NX] vt[NX] | wqb wkb wvb wob [4*NW] | tab (f32)
//   (attn output overwrites vb after vtrans consumed it)
// ---------------------------------------------------------------------------
extern "C" void kernel_launch(void* const* d_in, const int* in_sizes, int n_in,
                              void* d_out, int out_size, void* d_ws,
                              size_t ws_size, hipStream_t stream) {
    const float* query = (const float*)d_in[0];
    const float* key_  = (const float*)d_in[1];
    const float* value = (const float*)d_in[2];
    const float* wq    = (const float*)d_in[3];
    const float* bq    = (const float*)d_in[4];
    const float* wk    = (const float*)d_in[5];
    const float* bk    = (const float*)d_in[6];
    const float* wv    = (const float*)d_in[7];
    const float* bv    = (const float*)d_in[8];
    const float* wo    = (const float*)d_in[9];
    const float* bo    = (const float*)d_in[10];

    ushort* ws16 = (ushort*)d_ws;
    const size_t NX = (size_t)MROWS * EMB;   // 8388608 elem (16 MB bf16)
    const size_t NW = (size_t)EMB * EMB;     // 1048576 elem (2 MB bf16)
    ushort* qb  = ws16;
    ushort* kb  = qb + NX;
    ushort* vb  = kb + NX;                   // V, then attn output
    ushort* vt  = vb + NX;                   // V^T
    ushort* wqb = vt + NX;
    ushort* wkb = wqb + NW;
    ushort* wvb = wkb + NW;
    ushort* wob = wvb + NW;
    float*  tab = (float*)(wob + NW);

    const int nw4 = (int)(NW / 4);
    castw_kernel<<<dim3(nw4 / 256, 4), 256, 0, stream>>>(
        wq, wk, wv, wo, wqb, wkb, wvb, wob, nw4);
    xpos_tables_kernel<<<SEQ * HALF / 256, 256, 0, stream>>>(tab);

    qkv_gemm_kernel<<<dim3(512, 3), 256, 0, stream>>>(
        query, key_, value, wqb, wkb, wvb, bq, bk, bv, tab, qb, kb, vb);

    vtrans_kernel<<<dim3(16, 128), 256, 0, stream>>>(vb, vt);

    attn_kernel<<<2048, 256, 0, stream>>>(qb, kb, vt, vb);   // vb := attn out

    outproj_kernel<<<512, 256, 0, stream>>>(vb, wob, bo, (float*)d_out);
}

// Round 6
// 352.438 us; speedup vs baseline: 1.2157x; 1.2157x over previous
//
#include <hip/hip_runtime.h>

// ---------------------------------------------------------------------------
// XposMultiheadAttention (B=8, T=S=1024, E=1024, H=16, D=64) — r6 (r5 + fix)
// r3 structure (separate casts via shared tmp, proven 76MB ws) with the GEMMs
// upgraded to double-buffered 2-phase pipelines: stage(t+1) issued BEFORE the
// ds_read+MFMA phase of t, ONE __syncthreads per K-step (vmcnt drain at the
// barrier only waits the residual). Attention = r4 defer-max version.
// Fix vs r5: MODE=3 launch passes tab=nullptr (5-arg signature).
// ---------------------------------------------------------------------------

#define BSZ  8
#define SEQ  1024
#define EMB  1024
#define NH   16
#define HD   64
#define HALF 32
#define BH   (BSZ*NH)
#define MROWS (BSZ*SEQ)

typedef __attribute__((ext_vector_type(4))) float f32x4;
typedef __attribute__((ext_vector_type(8))) short bf16x8;

__device__ __forceinline__ ushort f2bf(float f) {
    union { float f; unsigned u; } v; v.f = f;
    return (ushort)((v.u + 0x7FFFu + ((v.u >> 16) & 1u)) >> 16);
}

// async global->LDS, 16B per lane; lds ptr must be the wave-uniform base.
__device__ __forceinline__ void async16(void* lds, const void* g) {
    __builtin_amdgcn_global_load_lds(
        (const __attribute__((address_space(1))) unsigned int*)g,
        (__attribute__((address_space(3))) unsigned int*)lds, 16, 0, 0);
}

// ---------------------------------------------------------------------------
// fp32 -> bf16 cast (vectorized)
// ---------------------------------------------------------------------------
__global__ __launch_bounds__(256)
void cast_kernel(const float* __restrict__ src, ushort* __restrict__ dst, int n4) {
    int i = blockIdx.x * 256 + threadIdx.x;
    if (i >= n4) return;
    float4 v = reinterpret_cast<const float4*>(src)[i];
    ushort4 o;
    o.x = f2bf(v.x); o.y = f2bf(v.y); o.z = f2bf(v.z); o.w = f2bf(v.w);
    reinterpret_cast<ushort4*>(dst)[i] = o;
}

// 4 weight casts in one launch (grid y = 0..3).
__global__ __launch_bounds__(256)
void castw_kernel(const float* __restrict__ w0, const float* __restrict__ w1,
                  const float* __restrict__ w2, const float* __restrict__ w3,
                  ushort* __restrict__ d0, ushort* __restrict__ d1,
                  ushort* __restrict__ d2, ushort* __restrict__ d3, int n4) {
    int i = blockIdx.x * 256 + threadIdx.x;
    if (i >= n4) return;
    const float* s = blockIdx.y == 0 ? w0 : blockIdx.y == 1 ? w1
                   : blockIdx.y == 2 ? w2 : w3;
    ushort* d = blockIdx.y == 0 ? d0 : blockIdx.y == 1 ? d1
              : blockIdx.y == 2 ? d2 : d3;
    float4 v = reinterpret_cast<const float4*>(s)[i];
    ushort4 o;
    o.x = f2bf(v.x); o.y = f2bf(v.y); o.z = f2bf(v.z); o.w = f2bf(v.w);
    reinterpret_cast<ushort4*>(d)[i] = o;
}

// ---------------------------------------------------------------------------
// xPos tables: [0]=sin*scale (q), [1]=cos*scale (q), [2]=sin/scale (k),
// [3]=cos/scale (k); each SEQ*HALF floats.
// ---------------------------------------------------------------------------
__global__ __launch_bounds__(256)
void xpos_tables_kernel(float* __restrict__ tab) {
    int idx = blockIdx.x * 256 + threadIdx.x;
    if (idx >= SEQ * HALF) return;
    int t = idx >> 5;
    int j = idx & 31;
    float s        = (2.0f * (float)j + 0.4f * (float)HD) / (1.4f * (float)HD);
    float pos      = (float)(t - SEQ / 2);
    float scale    = powf(s, pos * (1.0f / 1024.0f));
    float inv_freq = powf(10000.0f, -(float)j / (float)HALF);
    float ang      = (float)t * inv_freq;
    float sn = sinf(ang), cs = cosf(ang);
    float inv_scale = 1.0f / scale;
    tab[0 * SEQ * HALF + idx] = sn * scale;
    tab[1 * SEQ * HALF + idx] = cs * scale;
    tab[2 * SEQ * HALF + idx] = sn * inv_scale;
    tab[3 * SEQ * HALF + idx] = cs * inv_scale;
}

// ---------------------------------------------------------------------------
// bf16 MFMA GEMM, 2-phase double-buffered: Y[m,n] = sum_k A[m,k]*W[n,k]+bias.
// 128x128 tile, BK=64, 4 waves (2x2, each 64x64 = 4x4 frags 16x16x32).
// LDS: As/Bs 2 buffers each (64KB total). Element at byte (r*128+cb) holds
// global col ((cb ^ ((r&7)<<4))/2) — staged via pre-swizzled global source
// (global_load_lds writes linearly), read back with the same XOR (rule 21).
// Pipeline per K-step: issue stage(t+1) -> ds_read+MFMA(t) -> barrier
// (vmcnt drain only waits residual of loads issued one phase earlier).
// MODE: 0=v(bias), 1=q(bias,*0.125,xpos up), 2=k(bias,xpos down) -> bf16
// (B,H,T,D);   3=out-proj (A gathered from (B,H,T,D)) -> f32 (B,T,E).
// ---------------------------------------------------------------------------
template <int MODE>
__global__ __launch_bounds__(256)
void gemm_bf16_kernel(const ushort* __restrict__ A, const ushort* __restrict__ W,
                      const float* __restrict__ bias, const float* __restrict__ tab,
                      void* __restrict__ outp) {
    __shared__ ushort As[2][128 * 64];
    __shared__ ushort Bs[2][128 * 64];
    const int tid  = threadIdx.x;
    const int lane = tid & 63;
    const int w    = tid >> 6;
    const int g    = lane >> 4;
    const int c    = lane & 15;
    const int wr   = w >> 1, wc = w & 1;

    // XCD-contiguous remap (512 blocks, 8 XCDs).
    int lid = blockIdx.x;
    int wg  = (lid & 7) * 64 + (lid >> 3);
    const int row0 = (wg >> 3) * 128;
    const int col0 = (wg & 7) * 128;

    f32x4 acc[4][4] = {};

    int srow[4], scol[4];
    #pragma unroll
    for (int i = 0; i < 4; ++i) {
        int f = i * 4096 + tid * 16;          // byte offset in LDS tile
        int r = f >> 7, cb = f & 127;
        srow[i] = r;
        scol[i] = (cb ^ ((r & 7) << 4)) >> 1; // element idx, pre-swizzled
    }

    auto stage = [&](int buf, int k0) {
        #pragma unroll
        for (int i = 0; i < 4; ++i) {
            const ushort* srcA;
            if (MODE == 3) {
                int h = k0 >> 6;              // BK=64 == exactly one head
                srcA = &A[(((size_t)(row0 >> 10) * NH + h) * SEQ +
                           (row0 & 1023) + srow[i]) * HD + scol[i]];
            } else {
                srcA = &A[(size_t)(row0 + srow[i]) * EMB + k0 + scol[i]];
            }
            async16(&As[buf][i * 2048 + w * 512], srcA);
        }
        #pragma unroll
        for (int i = 0; i < 4; ++i)
            async16(&Bs[buf][i * 2048 + w * 512],
                    &W[(size_t)(col0 + srow[i]) * EMB + k0 + scol[i]]);
    };

    stage(0, 0);
    __syncthreads();                          // prologue drain (one exposure)

    for (int t = 0; t < 16; ++t) {
        const int cur = t & 1;
        if (t < 15) stage(cur ^ 1, (t + 1) * 64);   // in flight during MFMA

        const char* abase = reinterpret_cast<const char*>(As[cur]);
        const char* bbase = reinterpret_cast<const char*>(Bs[cur]);
        #pragma unroll
        for (int ks = 0; ks < 2; ++ks) {
            bf16x8 af[4], bfr[4];
            #pragma unroll
            for (int mi = 0; mi < 4; ++mi) {
                int r = wr * 64 + mi * 16 + c;
                af[mi] = *reinterpret_cast<const bf16x8*>(
                    abase + r * 128 + ((ks * 64 + g * 16) ^ ((r & 7) << 4)));
            }
            #pragma unroll
            for (int ni = 0; ni < 4; ++ni) {
                int r = wc * 64 + ni * 16 + c;
                bfr[ni] = *reinterpret_cast<const bf16x8*>(
                    bbase + r * 128 + ((ks * 64 + g * 16) ^ ((r & 7) << 4)));
            }
            #pragma unroll
            for (int mi = 0; mi < 4; ++mi)
                #pragma unroll
                for (int ni = 0; ni < 4; ++ni)
                    acc[mi][ni] = __builtin_amdgcn_mfma_f32_16x16x32_bf16(
                        af[mi], bfr[ni], acc[mi][ni], 0, 0, 0);
        }
        __syncthreads();   // drains residual vmcnt -> buf[cur^1] ready
    }

    // Epilogue. C map (m89): col n = col0+wc*64+ni*16+c, row m = ...+g*4+r.
    #pragma unroll
    for (int ni = 0; ni < 4; ++ni) {
        int n = col0 + wc * 64 + ni * 16 + c;
        float bn = bias[n];
        #pragma unroll
        for (int mi = 0; mi < 4; ++mi) {
            #pragma unroll
            for (int r = 0; r < 4; ++r) {
                int m = row0 + wr * 64 + mi * 16 + g * 4 + r;
                float val = acc[mi][ni][r] + bn;
                if (MODE == 1) val *= 0.125f;          // HEAD_DIM^-0.5
                if (MODE == 1 || MODE == 2) {          // xPos rotation
                    int t = m & (SEQ - 1);
                    int d = n & 63;
                    const int base = (MODE == 1 ? 0 : 2) * SEQ * HALF + t * HALF;
                    float sn = tab[base + (d >> 1)];
                    float cs = tab[base + SEQ * HALF + (d >> 1)];
                    float other = __shfl_xor(val, 1);  // partner col d^1
                    val = val * cs + ((d & 1) ? other * sn : -other * sn);
                }
                if (MODE == 3) {
                    ((float*)outp)[(size_t)m * EMB + n] = val;
                } else {
                    int b = m >> 10, t = m & 1023;
                    int h = n >> 6,  d = n & 63;
                    ((ushort*)outp)[(((size_t)b * NH + h) * SEQ + t) * HD + d] =
                        f2bf(val);
                }
            }
        }
    }
}

// ---------------------------------------------------------------------------
// V transpose: (B,H,T,D) bf16 -> (B,H,D,T) bf16, 64x64 tiles.
// ---------------------------------------------------------------------------
__global__ __launch_bounds__(256)
void vtrans_kernel(const ushort* __restrict__ v, ushort* __restrict__ vt) {
    __shared__ ushort T[64][72];
    const int tid = threadIdx.x;
    const int bh  = blockIdx.y;
    const int t0  = blockIdx.x * 64;
    const ushort* vb = &v[((size_t)bh * SEQ + t0) * HD];
    #pragma unroll
    for (int p = 0; p < 2; ++p) {
        int chunk = p * 256 + tid;
        int tl = chunk >> 3;
        int d8 = (chunk & 7) * 8;
        ushort tmp[8];
        *reinterpret_cast<uint4*>(tmp) =
            *reinterpret_cast<const uint4*>(&vb[tl * HD + d8]);
        #pragma unroll
        for (int j = 0; j < 8; ++j) T[d8 + j][tl] = tmp[j];
    }
    __syncthreads();
    ushort* ob = &vt[(size_t)bh * HD * SEQ + t0];
    #pragma unroll
    for (int p = 0; p < 2; ++p) {
        int chunk = p * 256 + tid;
        int dl = chunk >> 3;
        int t8 = (chunk & 7) * 8;
        *reinterpret_cast<uint4*>(&ob[(size_t)dl * SEQ + t8]) =
            *reinterpret_cast<const uint4*>(&T[dl][t8]);
    }
}

// ---------------------------------------------------------------------------
// Flash attention, bf16 MFMA, defer-max online softmax (r4, passing).
// Block = 64 q-rows of one (b,h); 4 waves x 16 q-rows. Q in regs; K and V^T
// 64x64 tiles double-buffered in swizzled LDS, stage-before-compute.
// Common path: no cross-lane ops, no rescale (m frozen unless local max
// exceeds m+8; P bounded by e^8). l lane-local, reduced once at the end.
// ---------------------------------------------------------------------------
__global__ __launch_bounds__(256)
void attn_kernel(const ushort* __restrict__ qg, const ushort* __restrict__ kg,
                 const ushort* __restrict__ vtg, ushort* __restrict__ og) {
    __shared__ ushort Ks[2 * 4096];
    __shared__ ushort Vs[2 * 4096];
    __shared__ ushort Ps[4096];
    const int tid  = threadIdx.x;
    const int lane = tid & 63;
    const int w    = tid >> 6;
    const int g    = lane >> 4;
    const int c    = lane & 15;

    int lid = blockIdx.x;                     // 2048 blocks
    int wg  = (lid & 7) * 256 + (lid >> 3);   // XCD-contiguous, bh-major
    const int bh = wg >> 4;
    const int q0 = (wg & 15) * 64;

    const ushort* qrow = &qg[((size_t)bh * SEQ + q0 + w * 16 + c) * HD];
    bf16x8 qf[2];
    qf[0] = *reinterpret_cast<const bf16x8*>(qrow + g * 8);
    qf[1] = *reinterpret_cast<const bf16x8*>(qrow + 32 + g * 8);

    float m_run[4], l_part[4];
    f32x4 oacc[4] = {};
    #pragma unroll
    for (int r = 0; r < 4; ++r) { m_run[r] = -1e30f; l_part[r] = 0.f; }

    int srow[2], scol[2];
    #pragma unroll
    for (int i = 0; i < 2; ++i) {
        int f = i * 4096 + tid * 16;
        int r = f >> 7, cb = f & 127;
        srow[i] = r; scol[i] = (cb ^ ((r & 7) << 4)) >> 1;
    }

    const ushort* kb  = &kg[(size_t)bh * SEQ * HD];
    const ushort* vtb = &vtg[(size_t)bh * HD * SEQ];

    auto stage = [&](int buf, int kt) {
        #pragma unroll
        for (int i = 0; i < 2; ++i) {
            async16(&Ks[buf * 4096 + i * 2048 + w * 512],
                    &kb[(size_t)(kt + srow[i]) * HD + scol[i]]);
            async16(&Vs[buf * 4096 + i * 2048 + w * 512],
                    &vtb[(size_t)srow[i] * SEQ + kt + scol[i]]);
        }
    };

    stage(0, 0);
    __syncthreads();

    char* pbase = reinterpret_cast<char*>(Ps) + w * 2048;

    for (int kt = 0; kt < SEQ; kt += 64) {
        const int cur = (kt >> 6) & 1;
        if (kt + 64 < SEQ) stage(cur ^ 1, kt + 64);  // prefetch overlaps compute

        const char* kbase = reinterpret_cast<const char*>(Ks) + cur * 8192;
        const char* vbase = reinterpret_cast<const char*>(Vs) + cur * 8192;

        // Scores: S[q=g*4+r][key=j*16+c]
        f32x4 s[4];
        #pragma unroll
        for (int j = 0; j < 4; ++j) {
            int key = j * 16 + c;
            int sw  = (key & 7) << 4;
            f32x4 a = {};
            #pragma unroll
            for (int ks = 0; ks < 2; ++ks) {
                bf16x8 kf = *reinterpret_cast<const bf16x8*>(
                    kbase + key * 128 + ((ks * 64 + g * 16) ^ sw));
                a = __builtin_amdgcn_mfma_f32_16x16x32_bf16(qf[ks], kf, a, 0, 0, 0);
            }
            s[j] = a;
        }

        // Defer-max: rescale only when some lane's local max exceeds m+8.
        float pmax[4];
        #pragma unroll
        for (int r = 0; r < 4; ++r)
            pmax[r] = fmaxf(fmaxf(s[0][r], s[1][r]), fmaxf(s[2][r], s[3][r]));
        int need = (pmax[0] > m_run[0] + 8.f) || (pmax[1] > m_run[1] + 8.f) ||
                   (pmax[2] > m_run[2] + 8.f) || (pmax[3] > m_run[3] + 8.f);
        if (__any(need)) {                    // wave-uniform branch (rare)
            #pragma unroll
            for (int r = 0; r < 4; ++r) {
                float mx = pmax[r];
                mx = fmaxf(mx, __shfl_xor(mx, 1));
                mx = fmaxf(mx, __shfl_xor(mx, 2));
                mx = fmaxf(mx, __shfl_xor(mx, 4));
                mx = fmaxf(mx, __shfl_xor(mx, 8));
                float mn = fmaxf(m_run[r], mx);
                float alpha = __expf(m_run[r] - mn);
                l_part[r] *= alpha;
                #pragma unroll
                for (int dblk = 0; dblk < 4; ++dblk) oacc[dblk][r] *= alpha;
                m_run[r] = mn;
            }
        }

        // P = exp(S - m), lane-local l partials, stage P (bf16, swizzled).
        #pragma unroll
        for (int r = 0; r < 4; ++r) {
            int q  = g * 4 + r;
            int sw = (q & 7) << 4;
            #pragma unroll
            for (int j = 0; j < 4; ++j) {
                float p = __expf(s[j][r] - m_run[r]);
                l_part[r] += p;
                int byt = q * 128 + (((j * 16 + c) * 2) ^ sw);
                *reinterpret_cast<ushort*>(pbase + byt) = f2bf(p);
            }
        }

        // PV: O[q][d] += P[q][key] * V^T[d][key]
        #pragma unroll
        for (int ks = 0; ks < 2; ++ks) {
            bf16x8 pf = *reinterpret_cast<const bf16x8*>(
                pbase + c * 128 + ((ks * 64 + g * 16) ^ ((c & 7) << 4)));
            #pragma unroll
            for (int dblk = 0; dblk < 4; ++dblk) {
                int d = dblk * 16 + c;
                bf16x8 vf = *reinterpret_cast<const bf16x8*>(
                    vbase + d * 128 + ((ks * 64 + g * 16) ^ ((d & 7) << 4)));
                oacc[dblk] = __builtin_amdgcn_mfma_f32_16x16x32_bf16(
                    pf, vf, oacc[dblk], 0, 0, 0);
            }
        }
        __syncthreads();   // drains prefetch vmcnt; all waves done with buf[cur]
    }

    // Epilogue: reduce l across the 16-lane row group, normalize, write bf16.
    #pragma unroll
    for (int r = 0; r < 4; ++r) {
        float rs = l_part[r];
        rs += __shfl_xor(rs, 1);
        rs += __shfl_xor(rs, 2);
        rs += __shfl_xor(rs, 4);
        rs += __shfl_xor(rs, 8);
        float inv = 1.f / rs;
        int q = q0 + w * 16 + g * 4 + r;
        #pragma unroll
        for (int dblk = 0; dblk < 4; ++dblk)
            og[((size_t)bh * SEQ + q) * HD + dblk * 16 + c] =
                f2bf(oacc[dblk][r] * inv);
    }
}

// ---------------------------------------------------------------------------
// Launch. ws (ushort units), 76 MB (r3-proven layout):
//   tmp[NX] (cast buf for q/k/v inputs, then V^T)
//   wqb|wkb|wvb|wob [4*NW] | tab (f32, 512KB) | qb[NX] kb[NX] vb[NX]
//   (vb reused as attn output after vtrans consumed V)
// ---------------------------------------------------------------------------
extern "C" void kernel_launch(void* const* d_in, const int* in_sizes, int n_in,
                              void* d_out, int out_size, void* d_ws,
                              size_t ws_size, hipStream_t stream) {
    const float* query = (const float*)d_in[0];
    const float* key_  = (const float*)d_in[1];
    const float* value = (const float*)d_in[2];
    const float* wq    = (const float*)d_in[3];
    const float* bq    = (const float*)d_in[4];
    const float* wk    = (const float*)d_in[5];
    const float* bk    = (const float*)d_in[6];
    const float* wv    = (const float*)d_in[7];
    const float* bv    = (const float*)d_in[8];
    const float* wo    = (const float*)d_in[9];
    const float* bo    = (const float*)d_in[10];

    ushort* ws16 = (ushort*)d_ws;
    const size_t NX = (size_t)MROWS * EMB;   // 8388608 elem (16 MB bf16)
    const size_t NW = (size_t)EMB * EMB;     // 1048576 elem (2 MB bf16)
    ushort* tmp = ws16;
    ushort* wqb = ws16 + NX;
    ushort* wkb = wqb + NW;
    ushort* wvb = wkb + NW;
    ushort* wob = wvb + NW;
    float*  tab = (float*)(wob + NW);
    ushort* qb  = (ushort*)(tab + 4 * SEQ * HALF);
    ushort* kb  = qb + NX;
    ushort* vb  = kb + NX;

    const int nx4 = (int)(NX / 4), nw4 = (int)(NW / 4);

    castw_kernel<<<dim3(nw4 / 256, 4), 256, 0, stream>>>(
        wq, wk, wv, wo, wqb, wkb, wvb, wob, nw4);
    xpos_tables_kernel<<<SEQ * HALF / 256, 256, 0, stream>>>(tab);

    cast_kernel<<<nx4 / 256, 256, 0, stream>>>(query, tmp, nx4);
    gemm_bf16_kernel<1><<<512, 256, 0, stream>>>(tmp, wqb, bq, tab, qb);
    cast_kernel<<<nx4 / 256, 256, 0, stream>>>(key_, tmp, nx4);
    gemm_bf16_kernel<2><<<512, 256, 0, stream>>>(tmp, wkb, bk, tab, kb);
    cast_kernel<<<nx4 / 256, 256, 0, stream>>>(value, tmp, nx4);
    gemm_bf16_kernel<0><<<512, 256, 0, stream>>>(tmp, wvb, bv, tab, vb);

    vtrans_kernel<<<dim3(16, 128), 256, 0, stream>>>(vb, tmp);  // tmp := V^T

    attn_kernel<<<2048, 256, 0, stream>>>(qb, kb, tmp, vb);     // vb := attn out

    gemm_bf16_kernel<3><<<512, 256, 0, stream>>>(vb, wob, bo, nullptr,
                                                 (float*)d_out);
}